// Round 1
// baseline (2824.316 us; speedup 1.0000x reference)
//
#include <hip/hip_runtime.h>

typedef float f32x4 __attribute__((ext_vector_type(4)));

#define T_STEPS 512
#define BATCH   64
#define NIN     512
#define H       1024
#define BH      (BATCH * H)   // 65536

// ---------------------------------------------------------------------------
// Kernel 1: transpose w_rec [j][h] -> wrecT [h][j]  (4 MB, one-time per call)
// ---------------------------------------------------------------------------
__global__ void transpose1024(const float* __restrict__ in, float* __restrict__ out) {
    __shared__ float tile[32][33];
    const int tx = threadIdx.x, ty = threadIdx.y;
    const int xg = blockIdx.x * 32 + tx;
    const int ybase = blockIdx.y * 32;
#pragma unroll
    for (int r = 0; r < 32; r += 8)
        tile[ty + r][tx] = in[(size_t)(ybase + ty + r) * H + xg];
    __syncthreads();
    const int x2 = blockIdx.y * 32 + tx;
    const int y2base = blockIdx.x * 32;
#pragma unroll
    for (int r = 0; r < 32; r += 8)
        out[(size_t)(y2base + ty + r) * H + x2] = tile[tx][ty + r];
}

// ---------------------------------------------------------------------------
// Kernel 2: cur[m][n] = sum_k x[m][k] * w_in[n][k]  (R7-verbatim, untouched)
// ---------------------------------------------------------------------------
#define BM 128
#define BN 128
#define BK 16
#define LDSS 132

__global__ __launch_bounds__(256) void gemm_xwin(const float* __restrict__ x,
                                                 const float* __restrict__ w,
                                                 float* __restrict__ cur) {
    __shared__ __align__(16) float As[BK][LDSS];
    __shared__ __align__(16) float Bs[BK][LDSS];
    const int tid = threadIdx.x;
    const int tx = tid & 15, ty = tid >> 4;
    const int tx4 = tx * 4, ty4 = ty * 4;
    const int m0 = blockIdx.y * BM;
    const int n0 = blockIdx.x * BN;

    float acc[8][8];
#pragma unroll
    for (int i = 0; i < 8; ++i)
#pragma unroll
        for (int j = 0; j < 8; ++j) acc[i][j] = 0.0f;

    const int ar = tid >> 2;
    const int akc = (tid & 3) * 4;

    for (int k0 = 0; k0 < NIN; k0 += BK) {
        const float4 a0 = *reinterpret_cast<const float4*>(&x[(size_t)(m0 + ar) * NIN + k0 + akc]);
        const float4 a1 = *reinterpret_cast<const float4*>(&x[(size_t)(m0 + ar + 64) * NIN + k0 + akc]);
        const float4 b0 = *reinterpret_cast<const float4*>(&w[(size_t)(n0 + ar) * NIN + k0 + akc]);
        const float4 b1 = *reinterpret_cast<const float4*>(&w[(size_t)(n0 + ar + 64) * NIN + k0 + akc]);
        __syncthreads();
        As[akc + 0][ar] = a0.x; As[akc + 1][ar] = a0.y; As[akc + 2][ar] = a0.z; As[akc + 3][ar] = a0.w;
        As[akc + 0][ar + 64] = a1.x; As[akc + 1][ar + 64] = a1.y; As[akc + 2][ar + 64] = a1.z; As[akc + 3][ar + 64] = a1.w;
        Bs[akc + 0][ar] = b0.x; Bs[akc + 1][ar] = b0.y; Bs[akc + 2][ar] = b0.z; Bs[akc + 3][ar] = b0.w;
        Bs[akc + 0][ar + 64] = b1.x; Bs[akc + 1][ar + 64] = b1.y; Bs[akc + 2][ar + 64] = b1.z; Bs[akc + 3][ar + 64] = b1.w;
        __syncthreads();

#pragma unroll
        for (int kk = 0; kk < BK; ++kk) {
            const float4 av0 = *reinterpret_cast<const float4*>(&As[kk][ty4]);
            const float4 av1 = *reinterpret_cast<const float4*>(&As[kk][ty4 + 64]);
            const float4 bv0 = *reinterpret_cast<const float4*>(&Bs[kk][tx4]);
            const float4 bv1 = *reinterpret_cast<const float4*>(&Bs[kk][tx4 + 64]);
            const float ar_[8] = {av0.x, av0.y, av0.z, av0.w, av1.x, av1.y, av1.z, av1.w};
            const float br_[8] = {bv0.x, bv0.y, bv0.z, bv0.w, bv1.x, bv1.y, bv1.z, bv1.w};
#pragma unroll
            for (int i = 0; i < 8; ++i)
#pragma unroll
                for (int j = 0; j < 8; ++j)
                    acc[i][j] = fmaf(ar_[i], br_[j], acc[i][j]);
        }
    }

#pragma unroll
    for (int gi = 0; gi < 2; ++gi)
#pragma unroll
        for (int ii = 0; ii < 4; ++ii) {
            const int i = gi * 4 + ii;
            const int row = m0 + ty4 + ii + gi * 64;
            float* dst = &cur[(size_t)row * H + n0 + tx4];
            *reinterpret_cast<float4*>(dst)      = make_float4(acc[i][0], acc[i][1], acc[i][2], acc[i][3]);
            *reinterpret_cast<float4*>(dst + 64) = make_float4(acc[i][4], acc[i][5], acc[i][6], acc[i][7]);
        }
}

// ---------------------------------------------------------------------------
// Kernel 3: sequential LSNN scan. One block per batch, 256 thr x 4 neurons.
//   R9: (a) the 4 per-wave spike lists are merged into ONE per-block list
//   (cross-wave prefix offsets; costs a 2nd s_barrier/step), (b) the gather
//   is a 2-deep x 16-row software pipeline (~32 f32x4 loads in flight vs the
//   old 8-deep drain-every-batch), (c) the first 2 batches are issued BEFORE
//   the dynamics/ballot/barrier phase so that VALU+sync work hides the first
//   load latency (raw s_barrier does NOT drain vmcnt), (d) the tail is one
//   masked batch via fmaf(mask, w, r) (exact no-op for mask=0) instead of a
//   serial loop, (e) row indices are readfirstlane'd so address math is SALU.
//   FP semantics are bit-identical to R8: the accumulation order of r
//   (wave 0..3 ascending, ascending h within wave, strictly sequential adds)
//   and every dynamics op are unchanged.
// ---------------------------------------------------------------------------
__global__ __launch_bounds__(256, 1) void lsnn_scan_kernel(float* __restrict__ io,
                                                           const float* __restrict__ wrecT) {
    const int b = blockIdx.x;
    const int tid = threadIdx.x;
    const int wave = tid >> 6, lane = tid & 63;
    const int j0 = tid * 4;

    __shared__ __align__(16) int list[2][1024];   // [phase][slot] merged list
    __shared__ __align__(16) int cnt[2][4];       // [phase][wave] per-wave counts

    float sv0 = 0.f, sv1 = 0.f, sv2 = 0.f, sv3 = 0.f;
    float si0 = 0.f, si1 = 0.f, si2 = 0.f, si3 = 0.f;
    float sb0 = 1.f, sb1 = 1.f, sb2 = 1.f, sb3 = 1.f;
    float sz0 = 0.f, sz1 = 0.f, sz2 = 0.f, sz3 = 0.f;
    int p = 0;

    const float C_MEM = (float)(1e-3 * 100.0);
    const float C_SYN = (float)(1e-3 * 200.0);
    const float C_AD  = (float)(1e-3 * (1.0 / 800.0));
    const float BETA  = 1.8f;

    float* base = io + (size_t)b * H + j0;

    if (lane == 0) cnt[0][wave] = 0;
    asm volatile("s_waitcnt lgkmcnt(0)" ::: "memory");
    __builtin_amdgcn_s_barrier();

    // chunk prefetch buffers: 8 steps of cur
    f32x4 P0 = *reinterpret_cast<const f32x4*>(base + (size_t)0 * BH);
    f32x4 P1 = *reinterpret_cast<const f32x4*>(base + (size_t)1 * BH);
    f32x4 P2 = *reinterpret_cast<const f32x4*>(base + (size_t)2 * BH);
    f32x4 P3 = *reinterpret_cast<const f32x4*>(base + (size_t)3 * BH);
    f32x4 P4 = *reinterpret_cast<const f32x4*>(base + (size_t)4 * BH);
    f32x4 P5 = *reinterpret_cast<const f32x4*>(base + (size_t)5 * BH);
    f32x4 P6 = *reinterpret_cast<const f32x4*>(base + (size_t)6 * BH);
    f32x4 P7 = *reinterpret_cast<const f32x4*>(base + (size_t)7 * BH);

#define GLOAD(DST, IDX)                                                       \
    DST = *reinterpret_cast<const f32x4*>(                                    \
        wrecT + (size_t)(unsigned)__builtin_amdgcn_readfirstlane(IDX) * H + j0)

#define LOAD16(BUF, A0)                                                       \
  {                                                                           \
    const int4 q0_ = *reinterpret_cast<const int4*>(lst + (A0));              \
    const int4 q1_ = *reinterpret_cast<const int4*>(lst + (A0) + 4);          \
    const int4 q2_ = *reinterpret_cast<const int4*>(lst + (A0) + 8);          \
    const int4 q3_ = *reinterpret_cast<const int4*>(lst + (A0) + 12);         \
    GLOAD(BUF[0],  q0_.x); GLOAD(BUF[1],  q0_.y);                             \
    GLOAD(BUF[2],  q0_.z); GLOAD(BUF[3],  q0_.w);                             \
    GLOAD(BUF[4],  q1_.x); GLOAD(BUF[5],  q1_.y);                             \
    GLOAD(BUF[6],  q1_.z); GLOAD(BUF[7],  q1_.w);                             \
    GLOAD(BUF[8],  q2_.x); GLOAD(BUF[9],  q2_.y);                             \
    GLOAD(BUF[10], q2_.z); GLOAD(BUF[11], q2_.w);                             \
    GLOAD(BUF[12], q3_.x); GLOAD(BUF[13], q3_.y);                             \
    GLOAD(BUF[14], q3_.z); GLOAD(BUF[15], q3_.w);                             \
  }

#define ACC16(BUF)                                                            \
  { _Pragma("unroll")                                                         \
    for (int k_ = 0; k_ < 16; ++k_) {                                         \
      r0 += BUF[k_].x; r1 += BUF[k_].y; r2 += BUF[k_].z; r3 += BUF[k_].w;     \
    } }

#define LOADT(BUF, A0)                                                        \
  {                                                                           \
    const int4 q0_ = *reinterpret_cast<const int4*>(lst + (A0));              \
    const int4 q1_ = *reinterpret_cast<const int4*>(lst + (A0) + 4);          \
    const int4 q2_ = *reinterpret_cast<const int4*>(lst + (A0) + 8);          \
    const int4 q3_ = *reinterpret_cast<const int4*>(lst + (A0) + 12);         \
    const int iv_[16] = {q0_.x, q0_.y, q0_.z, q0_.w, q1_.x, q1_.y, q1_.z,     \
                         q1_.w, q2_.x, q2_.y, q2_.z, q2_.w, q3_.x, q3_.y,     \
                         q3_.z, q3_.w};                                       \
    _Pragma("unroll")                                                         \
    for (int k_ = 0; k_ < 16; ++k_) {                                         \
      const int h_ = ((A0) + k_ < n) ? iv_[k_] : 0;                           \
      GLOAD(BUF[k_], h_);                                                     \
    }                                                                         \
  }

#define ACCT(BUF, A0)                                                         \
  { _Pragma("unroll")                                                         \
    for (int k_ = 0; k_ < 16; ++k_) {                                         \
      const float m_ = ((A0) + k_ < n) ? 1.0f : 0.0f;                         \
      r0 = fmaf(m_, BUF[k_].x, r0); r1 = fmaf(m_, BUF[k_].y, r1);             \
      r2 = fmaf(m_, BUF[k_].z, r2); r3 = fmaf(m_, BUF[k_].w, r3);             \
    } }

#define SCAN_STEP(T, CREG, PF)                                                \
  {                                                                           \
    const float cc0 = CREG.x, cc1 = CREG.y, cc2 = CREG.z, cc3 = CREG.w;       \
    const int4 cq = *reinterpret_cast<const int4*>(&cnt[p][0]);               \
    const int n = cq.x + cq.y + cq.z + cq.w;                                  \
    const int nb = n >> 4;                                                    \
    const int* lst = &list[p][0];                                             \
    f32x4 gA[16], gB[16], gT[16];                                             \
    float r0 = 0.f, r1 = 0.f, r2 = 0.f, r3 = 0.f;                             \
    /* prologue: issue first two batches before dynamics/ballot */            \
    if (nb > 0) LOAD16(gA, 0);                                                \
    if (nb > 1) LOAD16(gB, 16);                                               \
    /* dynamics (independent of this step's gather) */                        \
    const float vd0 = sv0 + C_MEM * (0.0f - sv0 + si0);                       \
    const float vd1 = sv1 + C_MEM * (0.0f - sv1 + si1);                       \
    const float vd2 = sv2 + C_MEM * (0.0f - sv2 + si2);                       \
    const float vd3 = sv3 + C_MEM * (0.0f - sv3 + si3);                       \
    const float id0 = si0 - C_SYN * si0;                                      \
    const float id1 = si1 - C_SYN * si1;                                      \
    const float id2 = si2 - C_SYN * si2;                                      \
    const float id3 = si3 - C_SYN * si3;                                      \
    const float bd0 = sb0 + C_AD * (1.0f - sb0);                              \
    const float bd1 = sb1 + C_AD * (1.0f - sb1);                              \
    const float bd2 = sb2 + C_AD * (1.0f - sb2);                              \
    const float bd3 = sb3 + C_AD * (1.0f - sb3);                              \
    sz0 = ((vd0 - bd0) > 0.0f) ? 1.0f : 0.0f;                                 \
    sz1 = ((vd1 - bd1) > 0.0f) ? 1.0f : 0.0f;                                 \
    sz2 = ((vd2 - bd2) > 0.0f) ? 1.0f : 0.0f;                                 \
    sz3 = ((vd3 - bd3) > 0.0f) ? 1.0f : 0.0f;                                 \
    sv0 = (sz0 > 0.0f) ? 0.0f : vd0;                                          \
    sv1 = (sz1 > 0.0f) ? 0.0f : vd1;                                          \
    sv2 = (sz2 > 0.0f) ? 0.0f : vd2;                                          \
    sv3 = (sz3 > 0.0f) ? 0.0f : vd3;                                          \
    sb0 = (sz0 > 0.0f) ? (bd0 + BETA) : bd0;                                  \
    sb1 = (sz1 > 0.0f) ? (bd1 + BETA) : bd1;                                  \
    sb2 = (sz2 > 0.0f) ? (bd2 + BETA) : bd2;                                  \
    sb3 = (sz3 > 0.0f) ? (bd3 + BETA) : bd3;                                  \
    if (PF) {                                                                 \
      if ((T) + 1 < T_STEPS) {                                                \
        const float* pb = base + (size_t)((T) + 1) * BH;                      \
        P0 = *(const f32x4*)(pb + (size_t)0 * BH);                            \
        P1 = *(const f32x4*)(pb + (size_t)1 * BH);                            \
        P2 = *(const f32x4*)(pb + (size_t)2 * BH);                            \
        P3 = *(const f32x4*)(pb + (size_t)3 * BH);                            \
        P4 = *(const f32x4*)(pb + (size_t)4 * BH);                            \
        P5 = *(const f32x4*)(pb + (size_t)5 * BH);                            \
        P6 = *(const f32x4*)(pb + (size_t)6 * BH);                            \
        P7 = *(const f32x4*)(pb + (size_t)7 * BH);                            \
      }                                                                       \
    }                                                                         \
    *reinterpret_cast<f32x4*>(base + (size_t)(T) * BH) =                      \
        (f32x4){sz0, sz1, sz2, sz3};                                          \
    const unsigned long long m0 = __ballot(sz0 > 0.0f);                       \
    const unsigned long long m1 = __ballot(sz1 > 0.0f);                       \
    const unsigned long long m2 = __ballot(sz2 > 0.0f);                       \
    const unsigned long long m3 = __ballot(sz3 > 0.0f);                       \
    unsigned pos = __builtin_amdgcn_mbcnt_hi((unsigned)(m0 >> 32),            \
                   __builtin_amdgcn_mbcnt_lo((unsigned)m0, 0u));              \
    pos = __builtin_amdgcn_mbcnt_hi((unsigned)(m1 >> 32),                     \
          __builtin_amdgcn_mbcnt_lo((unsigned)m1, pos));                      \
    pos = __builtin_amdgcn_mbcnt_hi((unsigned)(m2 >> 32),                     \
          __builtin_amdgcn_mbcnt_lo((unsigned)m2, pos));                      \
    pos = __builtin_amdgcn_mbcnt_hi((unsigned)(m3 >> 32),                     \
          __builtin_amdgcn_mbcnt_lo((unsigned)m3, pos));                      \
    if (lane == 0)                                                            \
      cnt[p ^ 1][wave] = __popcll(m0) + __popcll(m1) + __popcll(m2) + __popcll(m3); \
    asm volatile("s_waitcnt lgkmcnt(0)" ::: "memory");                        \
    __builtin_amdgcn_s_barrier();                                             \
    /* cross-wave prefix -> write entries into merged list */                 \
    const int4 nc = *reinterpret_cast<const int4*>(&cnt[p ^ 1][0]);           \
    const int woff = (wave > 0 ? nc.x : 0) + (wave > 1 ? nc.y : 0) +          \
                     (wave > 2 ? nc.z : 0);                                   \
    int* dst = &list[p ^ 1][woff];                                            \
    if (sz0 > 0.0f) dst[pos++] = j0 + 0;                                      \
    if (sz1 > 0.0f) dst[pos++] = j0 + 1;                                      \
    if (sz2 > 0.0f) dst[pos++] = j0 + 2;                                      \
    if (sz3 > 0.0f) dst[pos++] = j0 + 3;                                      \
    asm volatile("s_waitcnt lgkmcnt(0)" ::: "memory");                        \
    __builtin_amdgcn_s_barrier();                                             \
    /* issue masked tail batch (accumulated last, order preserved) */         \
    if (n & 15) LOADT(gT, nb << 4);                                           \
    /* drain the 2-deep pipeline: accumulate oldest, issue next */            \
    int a = 32;                                                               \
    bool useA = true;                                                         \
    for (int i = 2; i < nb; ++i) {                                            \
      if (useA) { ACC16(gA); LOAD16(gA, a); }                                 \
      else      { ACC16(gB); LOAD16(gB, a); }                                 \
      a += 16; useA = !useA;                                                  \
    }                                                                         \
    if (nb > 1) {                                                             \
      if (useA) { ACC16(gA); ACC16(gB); }                                     \
      else      { ACC16(gB); ACC16(gA); }                                     \
    } else if (nb == 1) {                                                     \
      ACC16(gA);                                                              \
    }                                                                         \
    if (n & 15) ACCT(gT, nb << 4);                                            \
    si0 = (id0 + cc0) + r0;                                                   \
    si1 = (id1 + cc1) + r1;                                                   \
    si2 = (id2 + cc2) + r2;                                                   \
    si3 = (id3 + cc3) + r3;                                                   \
    p ^= 1;                                                                   \
  }

    for (int t = 0; t < T_STEPS; t += 8) {
        SCAN_STEP(t,     P0, 0);
        SCAN_STEP(t + 1, P1, 0);
        SCAN_STEP(t + 2, P2, 0);
        SCAN_STEP(t + 3, P3, 0);
        SCAN_STEP(t + 4, P4, 0);
        SCAN_STEP(t + 5, P5, 0);
        SCAN_STEP(t + 6, P6, 0);
        SCAN_STEP(t + 7, P7, 1);
    }
#undef SCAN_STEP
#undef ACCT
#undef LOADT
#undef ACC16
#undef LOAD16
#undef GLOAD

    float* fo = io + (size_t)T_STEPS * BH + (size_t)b * H + j0;
    *reinterpret_cast<float4*>(fo)          = make_float4(sz0, sz1, sz2, sz3);
    *reinterpret_cast<float4*>(fo + BH)     = make_float4(sv0, sv1, sv2, sv3);
    *reinterpret_cast<float4*>(fo + 2 * BH) = make_float4(si0, si1, si2, si3);
    *reinterpret_cast<float4*>(fo + 3 * BH) = make_float4(sb0, sb1, sb2, sb3);
}

// ---------------------------------------------------------------------------
extern "C" void kernel_launch(void* const* d_in, const int* in_sizes, int n_in,
                              void* d_out, int out_size, void* d_ws, size_t ws_size,
                              hipStream_t stream) {
    const float* x     = (const float*)d_in[0];
    const float* w_in  = (const float*)d_in[1];
    const float* w_rec = (const float*)d_in[2];
    float* out   = (float*)d_out;
    float* wrecT = (float*)d_ws;

    transpose1024<<<dim3(H / 32, H / 32), dim3(32, 8), 0, stream>>>(w_rec, wrecT);
    gemm_xwin<<<dim3(H / BN, (T_STEPS * BATCH) / BM), 256, 0, stream>>>(x, w_in, out);
    lsnn_scan_kernel<<<BATCH, 256, 0, stream>>>(out, wrecT);
}